// Round 1
// baseline (1376.164 us; speedup 1.0000x reference)
//
#include <hip/hip_runtime.h>
#include <hip/hip_bf16.h>

#define Bn 4
#define Sn 1024
#define Dn 1024
#define Hn 16
#define DHn 64
#define BSn 4096
#define D2n 2048

typedef __attribute__((ext_vector_type(8))) short short8;
typedef __attribute__((ext_vector_type(8))) __bf16 bf16x8;
typedef __attribute__((ext_vector_type(4))) float floatx4;

static __device__ __forceinline__ unsigned short f2bf(float f) {
  union { float f; unsigned int u; } v; v.f = f;
  unsigned int u = v.u;
  u += 0x7fffu + ((u >> 16) & 1u);
  return (unsigned short)(u >> 16);
}

static __device__ __forceinline__ floatx4 mfma16(short8 a, short8 b, floatx4 c) {
  return __builtin_amdgcn_mfma_f32_16x16x32_bf16(
      __builtin_bit_cast(bf16x8, a), __builtin_bit_cast(bf16x8, b), c, 0, 0, 0);
}

// ---------------- fp32 -> bf16 convert ----------------
__global__ void k_cvt_bf16(const float* __restrict__ in,
                           unsigned short* __restrict__ out, int n) {
  int i = (blockIdx.x * 256 + threadIdx.x) * 4;
  if (i >= n) return;
  float4 v = *(const float4*)(in + i);
  ushort4 o;
  o.x = f2bf(v.x); o.y = f2bf(v.y); o.z = f2bf(v.z); o.w = f2bf(v.w);
  *(ushort4*)(out + i) = o;
}

// ---------------- shared MFMA core: wave computes 64x64 of A(MxK) @ W(NxK)^T
static __device__ __forceinline__ void gemm_core(
    const unsigned short* __restrict__ Aw, int lda,
    const unsigned short* __restrict__ Bw, int ldb,
    int K, floatx4 acc[4][4], int lane) {
  const int r = lane & 15, qd = lane >> 4;
  const unsigned short* ap = Aw + (size_t)r * lda + qd * 8;
  const unsigned short* bp = Bw + (size_t)r * ldb + qd * 8;
  for (int k0 = 0; k0 < K; k0 += 32) {
    short8 a[4], b[4];
#pragma unroll
    for (int i = 0; i < 4; ++i)
      a[i] = *(const short8*)(ap + (size_t)i * 16 * lda + k0);
#pragma unroll
    for (int j = 0; j < 4; ++j)
      b[j] = *(const short8*)(bp + (size_t)j * 16 * ldb + k0);
#pragma unroll
    for (int i = 0; i < 4; ++i)
#pragma unroll
      for (int j = 0; j < 4; ++j)
        acc[i][j] = mfma16(a[i], b[j], acc[i][j]);
  }
}

// ---------------- proj GEMM with bf16 output (q/k projections) ----------------
__global__ __launch_bounds__(256) void k_gemm_bf16out(
    const unsigned short* __restrict__ A, const unsigned short* __restrict__ W,
    const float* __restrict__ bias, unsigned short* __restrict__ Cout,
    int M, int N, int K) {
  const int lane = threadIdx.x & 63, w = threadIdx.x >> 6;
  const int m0 = blockIdx.y * 128 + (w >> 1) * 64;
  const int n0 = blockIdx.x * 128 + (w & 1) * 64;
  floatx4 acc[4][4] = {};
  gemm_core(A + (size_t)m0 * K, K, W + (size_t)n0 * K, K, K, acc, lane);
  const int r = lane & 15, qd = lane >> 4;
#pragma unroll
  for (int i = 0; i < 4; ++i)
#pragma unroll
    for (int j = 0; j < 4; ++j) {
      int col = n0 + j * 16 + r;
      float bv = bias[col];
#pragma unroll
      for (int rg = 0; rg < 4; ++rg) {
        int row = m0 + i * 16 + qd * 4 + rg;
        Cout[(size_t)row * N + col] = f2bf(acc[i][j][rg] + bv);
      }
    }
}

// ---------------- v projection, written transposed: vT[b][h][dh][s] bf16 -----
__global__ __launch_bounds__(256) void k_gemm_vT(
    const unsigned short* __restrict__ A, const unsigned short* __restrict__ W,
    const float* __restrict__ bias, unsigned short* __restrict__ vT) {
  const int lane = threadIdx.x & 63, w = threadIdx.x >> 6;
  const int m0 = blockIdx.y * 128 + (w >> 1) * 64;
  const int n0 = blockIdx.x * 128 + (w & 1) * 64;
  floatx4 acc[4][4] = {};
  gemm_core(A + (size_t)m0 * Dn, Dn, W + (size_t)n0 * Dn, Dn, Dn, acc, lane);
  const int r = lane & 15, qd = lane >> 4;
#pragma unroll
  for (int i = 0; i < 4; ++i)
#pragma unroll
    for (int j = 0; j < 4; ++j) {
      int col = n0 + j * 16 + r;   // d index: h*64+dh
      float bv = bias[col];
#pragma unroll
      for (int rg = 0; rg < 4; ++rg) {
        int row = m0 + i * 16 + qd * 4 + rg;   // b*1024 + s
        size_t idx = (((size_t)(row >> 10) * Hn + (col >> 6)) * DHn + (col & 63)) * Sn
                   + (row & 1023);
        vT[idx] = f2bf(acc[i][j][rg] + bv);
      }
    }
}

// ---------------- final GEMM: fp32 output ----------------
__global__ __launch_bounds__(256) void k_gemm_f32out(
    const unsigned short* __restrict__ A, const unsigned short* __restrict__ W,
    const float* __restrict__ bias, float* __restrict__ Cout,
    int M, int N, int K) {
  const int lane = threadIdx.x & 63, w = threadIdx.x >> 6;
  const int m0 = blockIdx.y * 128 + (w >> 1) * 64;
  const int n0 = blockIdx.x * 128 + (w & 1) * 64;
  floatx4 acc[4][4] = {};
  gemm_core(A + (size_t)m0 * K, K, W + (size_t)n0 * K, K, K, acc, lane);
  const int r = lane & 15, qd = lane >> 4;
#pragma unroll
  for (int i = 0; i < 4; ++i)
#pragma unroll
    for (int j = 0; j < 4; ++j) {
      int col = n0 + j * 16 + r;
      float bv = bias[col];
#pragma unroll
      for (int rg = 0; rg < 4; ++rg) {
        int row = m0 + i * 16 + qd * 4 + rg;
        Cout[(size_t)row * N + col] = acc[i][j][rg] + bv;
      }
    }
}

// ---------------- scores: raw masked scaled scores into attn region ----------
__global__ __launch_bounds__(256) void k_scores(
    const unsigned short* __restrict__ Qb, const unsigned short* __restrict__ Kb,
    const int* __restrict__ pad, float* __restrict__ out, int sel) {
  const int bh = blockIdx.z, b = bh >> 4, h = bh & 15;
  const int lane = threadIdx.x & 63, w = threadIdx.x >> 6;
  const int m0 = blockIdx.y * 128 + (w >> 1) * 64;
  const int n0 = blockIdx.x * 128 + (w & 1) * 64;
  const unsigned short* Abase = Qb + (size_t)b * Sn * D2n + sel * Dn + h * DHn;
  const unsigned short* Bbase = Kb + (size_t)b * Sn * D2n + sel * Dn + h * DHn;
  floatx4 acc[4][4] = {};
  gemm_core(Abase + (size_t)m0 * D2n, D2n, Bbase + (size_t)n0 * D2n, D2n, DHn,
            acc, lane);
  const int r = lane & 15, qd = lane >> 4;
  float* obase = out + (size_t)bh * Sn * Sn;
#pragma unroll
  for (int j = 0; j < 4; ++j) {
    int col = n0 + j * 16 + r;
    bool msk = (pad[b * Sn + col] == 0);
#pragma unroll
    for (int i = 0; i < 4; ++i)
#pragma unroll
      for (int rg = 0; rg < 4; ++rg) {
        int row = m0 + i * 16 + qd * 4 + rg;
        float s = acc[i][j][rg] * 0.125f;
        obase[(size_t)row * Sn + col] = msk ? -1e9f : s;
      }
  }
}

// ---------------- row softmax, in place, 1 wave per 1024-col row -------------
__global__ __launch_bounds__(256) void k_softmax(float* __restrict__ a) {
  const int row = blockIdx.x * 4 + (threadIdx.x >> 6);
  const int lane = threadIdx.x & 63;
  float* p = a + (size_t)row * 1024 + lane * 4;
  float4 v[4];
#pragma unroll
  for (int c = 0; c < 4; ++c) v[c] = *(const float4*)(p + c * 256);
  float mx = -1e30f;
#pragma unroll
  for (int c = 0; c < 4; ++c)
    mx = fmaxf(mx, fmaxf(fmaxf(v[c].x, v[c].y), fmaxf(v[c].z, v[c].w)));
  mx = fmaxf(mx, __shfl_xor(mx, 32));
  mx = fmaxf(mx, __shfl_xor(mx, 16));
  mx = fmaxf(mx, __shfl_xor(mx, 8));
  mx = fmaxf(mx, __shfl_xor(mx, 4));
  mx = fmaxf(mx, __shfl_xor(mx, 2));
  mx = fmaxf(mx, __shfl_xor(mx, 1));
  float sum = 0.f;
#pragma unroll
  for (int c = 0; c < 4; ++c) {
    v[c].x = __expf(v[c].x - mx); sum += v[c].x;
    v[c].y = __expf(v[c].y - mx); sum += v[c].y;
    v[c].z = __expf(v[c].z - mx); sum += v[c].z;
    v[c].w = __expf(v[c].w - mx); sum += v[c].w;
  }
  sum += __shfl_xor(sum, 32);
  sum += __shfl_xor(sum, 16);
  sum += __shfl_xor(sum, 8);
  sum += __shfl_xor(sum, 4);
  sum += __shfl_xor(sum, 2);
  sum += __shfl_xor(sum, 1);
  float inv = 1.0f / sum;
#pragma unroll
  for (int c = 0; c < 4; ++c) {
    v[c].x *= inv; v[c].y *= inv; v[c].z *= inv; v[c].w *= inv;
    *(float4*)(p + c * 256) = v[c];
  }
}

// ---------------- PV: ctx = (C .* (attn1 - lam*attn2)) @ V -------------------
__global__ __launch_bounds__(256) void k_pv(
    const float* __restrict__ attn1, const float* __restrict__ attn2,
    const float* __restrict__ Cm, const float* __restrict__ lam_p,
    const unsigned short* __restrict__ vT, float* __restrict__ ctx) {
  const int bh = blockIdx.y, b = bh >> 4, h = bh & 15;
  const int lane = threadIdx.x & 63, w = threadIdx.x >> 6;
  const int m0 = blockIdx.x * 256 + w * 64;
  const float lam = *lam_p;
  const int r = lane & 15, qd = lane >> 4;
  const float* a1 = attn1 + (size_t)bh * Sn * Sn;
  const float* a2 = attn2 + (size_t)bh * Sn * Sn;
  const float* cm = Cm + (size_t)b * Sn * Sn;
  const unsigned short* vh = vT + (size_t)bh * DHn * Sn;
  floatx4 acc[4][4] = {};
  for (int k0 = 0; k0 < Sn; k0 += 32) {
    short8 af[4];
#pragma unroll
    for (int i = 0; i < 4; ++i) {
      const size_t off = (size_t)(m0 + i * 16 + r) * Sn + k0 + qd * 8;
      float4 x0 = *(const float4*)(a1 + off);
      float4 x1 = *(const float4*)(a1 + off + 4);
      float4 y0 = *(const float4*)(a2 + off);
      float4 y1 = *(const float4*)(a2 + off + 4);
      float4 c0 = *(const float4*)(cm + off);
      float4 c1 = *(const float4*)(cm + off + 4);
      short8 t;
      t[0] = (short)f2bf(c0.x * (x0.x - lam * y0.x));
      t[1] = (short)f2bf(c0.y * (x0.y - lam * y0.y));
      t[2] = (short)f2bf(c0.z * (x0.z - lam * y0.z));
      t[3] = (short)f2bf(c0.w * (x0.w - lam * y0.w));
      t[4] = (short)f2bf(c1.x * (x1.x - lam * y1.x));
      t[5] = (short)f2bf(c1.y * (x1.y - lam * y1.y));
      t[6] = (short)f2bf(c1.z * (x1.z - lam * y1.z));
      t[7] = (short)f2bf(c1.w * (x1.w - lam * y1.w));
      af[i] = t;
    }
    short8 bf[4];
#pragma unroll
    for (int j = 0; j < 4; ++j)
      bf[j] = *(const short8*)(vh + (size_t)(j * 16 + r) * Sn + k0 + qd * 8);
#pragma unroll
    for (int i = 0; i < 4; ++i)
#pragma unroll
      for (int j = 0; j < 4; ++j)
        acc[i][j] = mfma16(af[i], bf[j], acc[i][j]);
  }
#pragma unroll
  for (int i = 0; i < 4; ++i)
#pragma unroll
    for (int j = 0; j < 4; ++j)
#pragma unroll
      for (int rg = 0; rg < 4; ++rg) {
        int row = m0 + i * 16 + qd * 4 + rg;
        int col = j * 16 + r;
        ctx[(size_t)(b * Sn + row) * Dn + h * DHn + col] = acc[i][j][rg];
      }
}

// ---------------- GroupNorm stats: one block per (b,h) group -----------------
__global__ __launch_bounds__(256) void k_gnstats(const float* __restrict__ ctx,
                                                 float* __restrict__ stats) {
  const int g = blockIdx.x, b = g >> 4, h = g & 15;
  const float* p = ctx + (size_t)b * Sn * Dn + h * DHn;
  float s = 0.f, s2 = 0.f;
  for (int idx = threadIdx.x; idx < Sn * DHn; idx += 256) {
    float v = p[(size_t)(idx >> 6) * Dn + (idx & 63)];
    s += v; s2 += v * v;
  }
  s += __shfl_xor(s, 32); s2 += __shfl_xor(s2, 32);
  s += __shfl_xor(s, 16); s2 += __shfl_xor(s2, 16);
  s += __shfl_xor(s, 8);  s2 += __shfl_xor(s2, 8);
  s += __shfl_xor(s, 4);  s2 += __shfl_xor(s2, 4);
  s += __shfl_xor(s, 2);  s2 += __shfl_xor(s2, 2);
  s += __shfl_xor(s, 1);  s2 += __shfl_xor(s2, 1);
  __shared__ float ls[4], ls2[4];
  const int lane = threadIdx.x & 63, w = threadIdx.x >> 6;
  if (lane == 0) { ls[w] = s; ls2[w] = s2; }
  __syncthreads();
  if (threadIdx.x == 0) {
    float S1 = ls[0] + ls[1] + ls[2] + ls[3];
    float S2 = ls2[0] + ls2[1] + ls2[2] + ls2[3];
    float mean = S1 * (1.f / 65536.f);
    float var = S2 * (1.f / 65536.f) - mean * mean;
    stats[g * 2] = mean;
    stats[g * 2 + 1] = rsqrtf(var + 1e-5f);
  }
}

// ---------------- normalize + gn affine + 0.2 scale -> bf16 ------------------
__global__ void k_norm(const float* __restrict__ ctx, const float* __restrict__ stats,
                       const float* __restrict__ gw, const float* __restrict__ gb,
                       unsigned short* __restrict__ outbf) {
  int i = (blockIdx.x * 256 + threadIdx.x) * 4;
  int d = i & (Dn - 1);
  int b = i >> 20;                   // i / (S*D)
  int g = b * Hn + (d >> 6);
  float mean = stats[g * 2], rstd = stats[g * 2 + 1];
  float4 v = *(const float4*)(ctx + i);
  float4 w4 = *(const float4*)(gw + d);
  float4 b4 = *(const float4*)(gb + d);
  ushort4 o;
  o.x = f2bf(((v.x - mean) * rstd * w4.x + b4.x) * 0.2f);
  o.y = f2bf(((v.y - mean) * rstd * w4.y + b4.y) * 0.2f);
  o.z = f2bf(((v.z - mean) * rstd * w4.z + b4.z) * 0.2f);
  o.w = f2bf(((v.w - mean) * rstd * w4.w + b4.w) * 0.2f);
  *(ushort4*)(outbf + i) = o;
}

extern "C" void kernel_launch(void* const* d_in, const int* in_sizes, int n_in,
                              void* d_out, int out_size, void* d_ws, size_t ws_size,
                              hipStream_t stream) {
  (void)in_sizes; (void)n_in; (void)out_size; (void)ws_size;
  const float* x     = (const float*)d_in[0];
  const float* lam   = (const float*)d_in[1];
  const float* Cmask = (const float*)d_in[2];
  const int*   pad   = (const int*)d_in[3];
  const float* wq    = (const float*)d_in[4];
  const float* wq_b  = (const float*)d_in[5];
  const float* wk    = (const float*)d_in[6];
  const float* wk_b  = (const float*)d_in[7];
  const float* wv    = (const float*)d_in[8];
  const float* wv_b  = (const float*)d_in[9];
  const float* ow    = (const float*)d_in[10];
  const float* ow_b  = (const float*)d_in[11];
  const float* gw    = (const float*)d_in[12];
  const float* gb    = (const float*)d_in[13];

  float* outp  = (float*)d_out;                       // [4096,1024]
  float* attn1 = outp + (size_t)BSn * Dn;             // [B,H,S,S] = 64Mi floats
  float* attn2 = attn1 + (size_t)Bn * Hn * Sn * Sn;

  char* wsb = (char*)d_ws;
  unsigned short* x_bf  = (unsigned short*)(wsb);                       // 8 MiB
  unsigned short* wq_bf = (unsigned short*)(wsb + ((size_t)8  << 20));  // 4 MiB
  unsigned short* wk_bf = (unsigned short*)(wsb + ((size_t)12 << 20));  // 4 MiB
  unsigned short* wv_bf = (unsigned short*)(wsb + ((size_t)16 << 20));  // 2 MiB
  unsigned short* ow_bf = (unsigned short*)(wsb + ((size_t)18 << 20));  // 2 MiB
  unsigned short* q_bf  = (unsigned short*)(wsb + ((size_t)20 << 20));  // 16 MiB
  unsigned short* k_bf  = (unsigned short*)(wsb + ((size_t)36 << 20));  // 16 MiB
  unsigned short* vT    = (unsigned short*)(wsb + ((size_t)52 << 20));  // 8 MiB
  float*          ctx   = (float*)(wsb + ((size_t)60 << 20));           // 16 MiB
  float*          stats = (float*)(wsb + ((size_t)76 << 20));           // 512 B
  unsigned short* sc_bf = x_bf;  // reuse x_bf region after projections

  // bf16 conversions
  k_cvt_bf16<<<4096, 256, 0, stream>>>(x,  x_bf,  BSn * Dn);
  k_cvt_bf16<<<2048, 256, 0, stream>>>(wq, wq_bf, D2n * Dn);
  k_cvt_bf16<<<2048, 256, 0, stream>>>(wk, wk_bf, D2n * Dn);
  k_cvt_bf16<<<1024, 256, 0, stream>>>(wv, wv_bf, Dn * Dn);
  k_cvt_bf16<<<1024, 256, 0, stream>>>(ow, ow_bf, Dn * Dn);

  // projections
  k_gemm_bf16out<<<dim3(16, 32), 256, 0, stream>>>(x_bf, wq_bf, wq_b, q_bf,
                                                   BSn, D2n, Dn);
  k_gemm_bf16out<<<dim3(16, 32), 256, 0, stream>>>(x_bf, wk_bf, wk_b, k_bf,
                                                   BSn, D2n, Dn);
  k_gemm_vT<<<dim3(8, 32), 256, 0, stream>>>(x_bf, wv_bf, wv_b, vT);

  // raw masked scores into d_out attn regions
  k_scores<<<dim3(8, 8, Bn * Hn), 256, 0, stream>>>(q_bf, k_bf, pad, attn1, 0);
  k_scores<<<dim3(8, 8, Bn * Hn), 256, 0, stream>>>(q_bf, k_bf, pad, attn2, 1);

  // softmax in place over attn1 and attn2 together (contiguous rows)
  k_softmax<<<(2 * Bn * Hn * Sn) / 4, 256, 0, stream>>>(attn1);

  // PV with on-the-fly combined = C .* (attn1 - lam*attn2)
  k_pv<<<dim3(4, Bn * Hn), 256, 0, stream>>>(attn1, attn2, Cmask, lam, vT, ctx);

  // GroupNorm + scale, then output projection
  k_gnstats<<<Bn * Hn, 256, 0, stream>>>(ctx, stats);
  k_norm<<<4096, 256, 0, stream>>>(ctx, stats, gw, gb, sc_bf);
  k_gemm_f32out<<<dim3(8, 32), 256, 0, stream>>>(sc_bf, ow_bf, ow_b, outp,
                                                 BSn, Dn, Dn);
}

// Round 2
// 1137.915 us; speedup vs baseline: 1.2094x; 1.2094x over previous
//
#include <hip/hip_runtime.h>
#include <hip/hip_bf16.h>

#define Bn 4
#define Sn 1024
#define Dn 1024
#define Hn 16
#define DHn 64
#define BSn 4096
#define D2n 2048

typedef __attribute__((ext_vector_type(8))) short short8;
typedef __attribute__((ext_vector_type(8))) __bf16 bf16x8;
typedef __attribute__((ext_vector_type(4))) float floatx4;

static __device__ __forceinline__ unsigned short f2bf(float f) {
  union { float f; unsigned int u; } v; v.f = f;
  unsigned int u = v.u;
  u += 0x7fffu + ((u >> 16) & 1u);
  return (unsigned short)(u >> 16);
}

static __device__ __forceinline__ float bf2f(unsigned short s) {
  union { unsigned int u; float f; } v;
  v.u = ((unsigned int)s) << 16;
  return v.f;
}

static __device__ __forceinline__ floatx4 mfma16(short8 a, short8 b, floatx4 c) {
  return __builtin_amdgcn_mfma_f32_16x16x32_bf16(
      __builtin_bit_cast(bf16x8, a), __builtin_bit_cast(bf16x8, b), c, 0, 0, 0);
}

// ---------------- fp32 -> bf16 convert ----------------
__global__ void k_cvt_bf16(const float* __restrict__ in,
                           unsigned short* __restrict__ out, int n) {
  int i = (blockIdx.x * 256 + threadIdx.x) * 4;
  if (i >= n) return;
  float4 v = *(const float4*)(in + i);
  ushort4 o;
  o.x = f2bf(v.x); o.y = f2bf(v.y); o.z = f2bf(v.z); o.w = f2bf(v.w);
  *(ushort4*)(out + i) = o;
}

// ---------------- shared MFMA core: wave computes 64x64 of A(MxK) @ W(NxK)^T
static __device__ __forceinline__ void gemm_core(
    const unsigned short* __restrict__ Aw, int lda,
    const unsigned short* __restrict__ Bw, int ldb,
    int K, floatx4 acc[4][4], int lane) {
  const int r = lane & 15, qd = lane >> 4;
  const unsigned short* ap = Aw + (size_t)r * lda + qd * 8;
  const unsigned short* bp = Bw + (size_t)r * ldb + qd * 8;
  for (int k0 = 0; k0 < K; k0 += 32) {
    short8 a[4], b[4];
#pragma unroll
    for (int i = 0; i < 4; ++i)
      a[i] = *(const short8*)(ap + (size_t)i * 16 * lda + k0);
#pragma unroll
    for (int j = 0; j < 4; ++j)
      b[j] = *(const short8*)(bp + (size_t)j * 16 * ldb + k0);
#pragma unroll
    for (int i = 0; i < 4; ++i)
#pragma unroll
      for (int j = 0; j < 4; ++j)
        acc[i][j] = mfma16(a[i], b[j], acc[i][j]);
  }
}

// ---------------- proj GEMM with bf16 output (q/k projections) ----------------
__global__ __launch_bounds__(256) void k_gemm_bf16out(
    const unsigned short* __restrict__ A, const unsigned short* __restrict__ W,
    const float* __restrict__ bias, unsigned short* __restrict__ Cout,
    int M, int N, int K) {
  const int lane = threadIdx.x & 63, w = threadIdx.x >> 6;
  const int m0 = blockIdx.y * 128 + (w >> 1) * 64;
  const int n0 = blockIdx.x * 128 + (w & 1) * 64;
  floatx4 acc[4][4] = {};
  gemm_core(A + (size_t)m0 * K, K, W + (size_t)n0 * K, K, K, acc, lane);
  const int r = lane & 15, qd = lane >> 4;
#pragma unroll
  for (int i = 0; i < 4; ++i)
#pragma unroll
    for (int j = 0; j < 4; ++j) {
      int col = n0 + j * 16 + r;
      float bv = bias[col];
#pragma unroll
      for (int rg = 0; rg < 4; ++rg) {
        int row = m0 + i * 16 + qd * 4 + rg;
        Cout[(size_t)row * N + col] = f2bf(acc[i][j][rg] + bv);
      }
    }
}

// ---------------- v projection, written transposed: vT[b][h][dh][s] bf16 -----
__global__ __launch_bounds__(256) void k_gemm_vT(
    const unsigned short* __restrict__ A, const unsigned short* __restrict__ W,
    const float* __restrict__ bias, unsigned short* __restrict__ vT) {
  const int lane = threadIdx.x & 63, w = threadIdx.x >> 6;
  const int m0 = blockIdx.y * 128 + (w >> 1) * 64;
  const int n0 = blockIdx.x * 128 + (w & 1) * 64;
  floatx4 acc[4][4] = {};
  gemm_core(A + (size_t)m0 * Dn, Dn, W + (size_t)n0 * Dn, Dn, Dn, acc, lane);
  const int r = lane & 15, qd = lane >> 4;
#pragma unroll
  for (int i = 0; i < 4; ++i)
#pragma unroll
    for (int j = 0; j < 4; ++j) {
      int col = n0 + j * 16 + r;   // d index: h*64+dh
      float bv = bias[col];
#pragma unroll
      for (int rg = 0; rg < 4; ++rg) {
        int row = m0 + i * 16 + qd * 4 + rg;   // b*1024 + s
        size_t idx = (((size_t)(row >> 10) * Hn + (col >> 6)) * DHn + (col & 63)) * Sn
                   + (row & 1023);
        vT[idx] = f2bf(acc[i][j][rg] + bv);
      }
    }
}

// ---------------- final GEMM: fp32 output ----------------
__global__ __launch_bounds__(256) void k_gemm_f32out(
    const unsigned short* __restrict__ A, const unsigned short* __restrict__ W,
    const float* __restrict__ bias, float* __restrict__ Cout,
    int M, int N, int K) {
  const int lane = threadIdx.x & 63, w = threadIdx.x >> 6;
  const int m0 = blockIdx.y * 128 + (w >> 1) * 64;
  const int n0 = blockIdx.x * 128 + (w & 1) * 64;
  floatx4 acc[4][4] = {};
  gemm_core(A + (size_t)m0 * K, K, W + (size_t)n0 * K, K, K, acc, lane);
  const int r = lane & 15, qd = lane >> 4;
#pragma unroll
  for (int i = 0; i < 4; ++i)
#pragma unroll
    for (int j = 0; j < 4; ++j) {
      int col = n0 + j * 16 + r;
      float bv = bias[col];
#pragma unroll
      for (int rg = 0; rg < 4; ++rg) {
        int row = m0 + i * 16 + qd * 4 + rg;
        Cout[(size_t)row * N + col] = acc[i][j][rg] + bv;
      }
    }
}

// ---------------- fused attention: QK -> softmax -> write attn -> combine -> PV
// One block = 16 query rows of one (b,h). 4 waves; wave w owns cols [w*256,w*256+256).
__global__ __launch_bounds__(256) void k_attn_fused(
    const unsigned short* __restrict__ q_bf, const unsigned short* __restrict__ k_bf,
    const int* __restrict__ pad, const float* __restrict__ Cm,
    const float* __restrict__ lam_p, const unsigned short* __restrict__ vT,
    float* __restrict__ attn1, float* __restrict__ attn2, float* __restrict__ ctx) {
  __shared__ __align__(16) unsigned short lds_a[16][1032];  // bf16 attn1 / combined
  __shared__ float smax[4][16];
  __shared__ float ssum[4][16];

  const int bh = blockIdx.y, b = bh >> 4, h = bh & 15;
  const int m0 = blockIdx.x * 16;
  const int lane = threadIdx.x & 63, w = threadIdx.x >> 6;
  const int r = lane & 15, qd = lane >> 4;
  const float lam = *lam_p;

  const unsigned short* qrow = q_bf + ((size_t)(b * Sn + m0 + r)) * D2n + h * DHn;
  const unsigned short* kb   = k_bf + ((size_t)(b * Sn)) * D2n + h * DHn;

  bool msk[16];
#pragma unroll
  for (int j = 0; j < 16; ++j)
    msk[j] = (pad[b * Sn + w * 256 + j * 16 + r] == 0);

  floatx4 acc[16];

  for (int sel = 0; sel < 2; ++sel) {
    short8 a0 = *(const short8*)(qrow + sel * Dn + qd * 8);
    short8 a1 = *(const short8*)(qrow + sel * Dn + 32 + qd * 8);
#pragma unroll
    for (int j = 0; j < 16; ++j) acc[j] = floatx4{0.f, 0.f, 0.f, 0.f};
#pragma unroll
    for (int j = 0; j < 16; ++j) {
      const unsigned short* kp =
          kb + (size_t)(w * 256 + j * 16 + r) * D2n + sel * Dn + qd * 8;
      short8 b0 = *(const short8*)(kp);
      short8 b1 = *(const short8*)(kp + 32);
      acc[j] = mfma16(a0, b0, acc[j]);
      acc[j] = mfma16(a1, b1, acc[j]);
    }
#pragma unroll
    for (int j = 0; j < 16; ++j)
#pragma unroll
      for (int rg = 0; rg < 4; ++rg)
        acc[j][rg] = msk[j] ? -1e9f : acc[j][rg] * 0.125f;

    // row max: rows qd*4+rg; lanes sharing qd share rows (xor over r bits)
    float mx[4];
#pragma unroll
    for (int rg = 0; rg < 4; ++rg) {
      float m = acc[0][rg];
#pragma unroll
      for (int j = 1; j < 16; ++j) m = fmaxf(m, acc[j][rg]);
      m = fmaxf(m, __shfl_xor(m, 1));
      m = fmaxf(m, __shfl_xor(m, 2));
      m = fmaxf(m, __shfl_xor(m, 4));
      m = fmaxf(m, __shfl_xor(m, 8));
      mx[rg] = m;
    }
    if (r == 0)
#pragma unroll
      for (int rg = 0; rg < 4; ++rg) smax[w][qd * 4 + rg] = mx[rg];
    __syncthreads();
#pragma unroll
    for (int rg = 0; rg < 4; ++rg)
      mx[rg] = fmaxf(fmaxf(smax[0][qd * 4 + rg], smax[1][qd * 4 + rg]),
                     fmaxf(smax[2][qd * 4 + rg], smax[3][qd * 4 + rg]));

    float sm[4] = {0.f, 0.f, 0.f, 0.f};
#pragma unroll
    for (int j = 0; j < 16; ++j)
#pragma unroll
      for (int rg = 0; rg < 4; ++rg) {
        float e = __expf(acc[j][rg] - mx[rg]);
        acc[j][rg] = e;
        sm[rg] += e;
      }
#pragma unroll
    for (int rg = 0; rg < 4; ++rg) {
      float s = sm[rg];
      s += __shfl_xor(s, 1);
      s += __shfl_xor(s, 2);
      s += __shfl_xor(s, 4);
      s += __shfl_xor(s, 8);
      sm[rg] = s;
    }
    if (r == 0)
#pragma unroll
      for (int rg = 0; rg < 4; ++rg) ssum[w][qd * 4 + rg] = sm[rg];
    __syncthreads();
    float inv[4];
#pragma unroll
    for (int rg = 0; rg < 4; ++rg)
      inv[rg] = 1.0f / (ssum[0][qd * 4 + rg] + ssum[1][qd * 4 + rg] +
                        ssum[2][qd * 4 + rg] + ssum[3][qd * 4 + rg]);

    float* ao = (sel == 0 ? attn1 : attn2) + (size_t)bh * Sn * Sn;
#pragma unroll
    for (int j = 0; j < 16; ++j)
#pragma unroll
      for (int rg = 0; rg < 4; ++rg) {
        float v = acc[j][rg] * inv[rg];
        acc[j][rg] = v;
        ao[(size_t)(m0 + qd * 4 + rg) * Sn + w * 256 + j * 16 + r] = v;
      }
    if (sel == 0) {
      // stash attn1 (bf16) in LDS; same-lane positions -> wave-ordered, no barrier
#pragma unroll
      for (int j = 0; j < 16; ++j)
#pragma unroll
        for (int rg = 0; rg < 4; ++rg)
          lds_a[qd * 4 + rg][w * 256 + j * 16 + r] = f2bf(acc[j][rg]);
    }
  }

  // combine in place: lds_a <- C .* (attn1 - lam*attn2)   (acc holds attn2)
  const float* cbase = Cm + ((size_t)(b * Sn + m0)) * Sn;
#pragma unroll
  for (int j = 0; j < 16; ++j)
#pragma unroll
    for (int rg = 0; rg < 4; ++rg) {
      int row = qd * 4 + rg, col = w * 256 + j * 16 + r;
      float a1v = bf2f(lds_a[row][col]);
      float cv = cbase[(size_t)row * Sn + col];
      lds_a[row][col] = f2bf(cv * (a1v - lam * acc[j][rg]));
    }
  __syncthreads();

  // PV: wave w accumulates over its k-quarter; cross-wave reduce via LDS
  const unsigned short* vh = vT + (size_t)bh * DHn * Sn;
  floatx4 pv[4] = {};
  for (int k0 = 0; k0 < 256; k0 += 32) {
    short8 af = *(const short8*)(&lds_a[r][w * 256 + k0 + qd * 8]);
#pragma unroll
    for (int j = 0; j < 4; ++j) {
      short8 bf = *(const short8*)(vh + (size_t)(j * 16 + r) * Sn + w * 256 + k0 + qd * 8);
      pv[j] = mfma16(af, bf, pv[j]);
    }
  }
  __syncthreads();  // all PV reads of lds_a done; reuse as reduction buffer
  float* redp = (float*)&lds_a[0][0];  // 4 x 1024 floats = 16 KB (fits in 33 KB)
#pragma unroll
  for (int j = 0; j < 4; ++j)
#pragma unroll
    for (int rg = 0; rg < 4; ++rg)
      redp[w * 1024 + (qd * 4 + rg) * 64 + j * 16 + r] = pv[j][rg];
  __syncthreads();
#pragma unroll
  for (int ii = 0; ii < 4; ++ii) {
    int e = threadIdx.x + ii * 256;
    float s = redp[e] + redp[1024 + e] + redp[2048 + e] + redp[3072 + e];
    int rr = e >> 6, cc = e & 63;
    ctx[((size_t)(b * Sn + m0 + rr)) * Dn + h * DHn + cc] = s;
  }
}

// ---------------- GroupNorm stats: one block per (b,h) group -----------------
__global__ __launch_bounds__(256) void k_gnstats(const float* __restrict__ ctx,
                                                 float* __restrict__ stats) {
  const int g = blockIdx.x, b = g >> 4, h = g & 15;
  const float* p = ctx + (size_t)b * Sn * Dn + h * DHn;
  float s = 0.f, s2 = 0.f;
  for (int idx = threadIdx.x; idx < Sn * DHn; idx += 256) {
    float v = p[(size_t)(idx >> 6) * Dn + (idx & 63)];
    s += v; s2 += v * v;
  }
  s += __shfl_xor(s, 32); s2 += __shfl_xor(s2, 32);
  s += __shfl_xor(s, 16); s2 += __shfl_xor(s2, 16);
  s += __shfl_xor(s, 8);  s2 += __shfl_xor(s2, 8);
  s += __shfl_xor(s, 4);  s2 += __shfl_xor(s2, 4);
  s += __shfl_xor(s, 2);  s2 += __shfl_xor(s2, 2);
  s += __shfl_xor(s, 1);  s2 += __shfl_xor(s2, 1);
  __shared__ float ls[4], ls2[4];
  const int lane = threadIdx.x & 63, w = threadIdx.x >> 6;
  if (lane == 0) { ls[w] = s; ls2[w] = s2; }
  __syncthreads();
  if (threadIdx.x == 0) {
    float S1 = ls[0] + ls[1] + ls[2] + ls[3];
    float S2 = ls2[0] + ls2[1] + ls2[2] + ls2[3];
    float mean = S1 * (1.f / 65536.f);
    float var = S2 * (1.f / 65536.f) - mean * mean;
    stats[g * 2] = mean;
    stats[g * 2 + 1] = rsqrtf(var + 1e-5f);
  }
}

// ---------------- normalize + gn affine + 0.2 scale -> bf16 ------------------
__global__ void k_norm(const float* __restrict__ ctx, const float* __restrict__ stats,
                       const float* __restrict__ gw, const float* __restrict__ gb,
                       unsigned short* __restrict__ outbf) {
  int i = (blockIdx.x * 256 + threadIdx.x) * 4;
  int d = i & (Dn - 1);
  int b = i >> 20;                   // i / (S*D)
  int g = b * Hn + (d >> 6);
  float mean = stats[g * 2], rstd = stats[g * 2 + 1];
  float4 v = *(const float4*)(ctx + i);
  float4 w4 = *(const float4*)(gw + d);
  float4 b4 = *(const float4*)(gb + d);
  ushort4 o;
  o.x = f2bf(((v.x - mean) * rstd * w4.x + b4.x) * 0.2f);
  o.y = f2bf(((v.y - mean) * rstd * w4.y + b4.y) * 0.2f);
  o.z = f2bf(((v.z - mean) * rstd * w4.z + b4.z) * 0.2f);
  o.w = f2bf(((v.w - mean) * rstd * w4.w + b4.w) * 0.2f);
  *(ushort4*)(outbf + i) = o;
}

extern "C" void kernel_launch(void* const* d_in, const int* in_sizes, int n_in,
                              void* d_out, int out_size, void* d_ws, size_t ws_size,
                              hipStream_t stream) {
  (void)in_sizes; (void)n_in; (void)out_size; (void)ws_size;
  const float* x     = (const float*)d_in[0];
  const float* lam   = (const float*)d_in[1];
  const float* Cmask = (const float*)d_in[2];
  const int*   pad   = (const int*)d_in[3];
  const float* wq    = (const float*)d_in[4];
  const float* wq_b  = (const float*)d_in[5];
  const float* wk    = (const float*)d_in[6];
  const float* wk_b  = (const float*)d_in[7];
  const float* wv    = (const float*)d_in[8];
  const float* wv_b  = (const float*)d_in[9];
  const float* ow    = (const float*)d_in[10];
  const float* ow_b  = (const float*)d_in[11];
  const float* gw    = (const float*)d_in[12];
  const float* gb    = (const float*)d_in[13];

  float* outp  = (float*)d_out;                       // [4096,1024]
  float* attn1 = outp + (size_t)BSn * Dn;             // [B,H,S,S]
  float* attn2 = attn1 + (size_t)Bn * Hn * Sn * Sn;

  char* wsb = (char*)d_ws;
  unsigned short* x_bf  = (unsigned short*)(wsb);                       // 8 MiB
  unsigned short* wq_bf = (unsigned short*)(wsb + ((size_t)8  << 20));  // 4 MiB
  unsigned short* wk_bf = (unsigned short*)(wsb + ((size_t)12 << 20));  // 4 MiB
  unsigned short* wv_bf = (unsigned short*)(wsb + ((size_t)16 << 20));  // 2 MiB
  unsigned short* ow_bf = (unsigned short*)(wsb + ((size_t)18 << 20));  // 2 MiB
  unsigned short* q_bf  = (unsigned short*)(wsb + ((size_t)20 << 20));  // 16 MiB
  unsigned short* k_bf  = (unsigned short*)(wsb + ((size_t)36 << 20));  // 16 MiB
  unsigned short* vT    = (unsigned short*)(wsb + ((size_t)52 << 20));  // 8 MiB
  float*          ctx   = (float*)(wsb + ((size_t)60 << 20));           // 16 MiB
  float*          stats = (float*)(wsb + ((size_t)76 << 20));           // 512 B
  unsigned short* sc_bf = x_bf;  // reuse x_bf region after projections

  // bf16 conversions
  k_cvt_bf16<<<4096, 256, 0, stream>>>(x,  x_bf,  BSn * Dn);
  k_cvt_bf16<<<2048, 256, 0, stream>>>(wq, wq_bf, D2n * Dn);
  k_cvt_bf16<<<2048, 256, 0, stream>>>(wk, wk_bf, D2n * Dn);
  k_cvt_bf16<<<1024, 256, 0, stream>>>(wv, wv_bf, Dn * Dn);
  k_cvt_bf16<<<1024, 256, 0, stream>>>(ow, ow_bf, Dn * Dn);

  // projections
  k_gemm_bf16out<<<dim3(16, 32), 256, 0, stream>>>(x_bf, wq_bf, wq_b, q_bf,
                                                   BSn, D2n, Dn);
  k_gemm_bf16out<<<dim3(16, 32), 256, 0, stream>>>(x_bf, wk_bf, wk_b, k_bf,
                                                   BSn, D2n, Dn);
  k_gemm_vT<<<dim3(8, 32), 256, 0, stream>>>(x_bf, wv_bf, wv_b, vT);

  // fused attention: scores -> softmax -> attn writes -> combine -> PV -> ctx
  k_attn_fused<<<dim3(Sn / 16, Bn * Hn), 256, 0, stream>>>(
      q_bf, k_bf, pad, Cmask, lam, vT, attn1, attn2, ctx);

  // GroupNorm + scale, then output projection
  k_gnstats<<<Bn * Hn, 256, 0, stream>>>(ctx, stats);
  k_norm<<<4096, 256, 0, stream>>>(ctx, stats, gw, gb, sc_bf);
  k_gemm_f32out<<<dim3(8, 32), 256, 0, stream>>>(sc_bf, ow_bf, ow_b, outp,
                                                 BSn, Dn, Dn);
}